// Round 9
// baseline (75.939 us; speedup 1.0000x reference)
//
#include <hip/hip_runtime.h>

#define NB  16   // batch
#define NN  64   // nodes
#define NFD 64   // node features
#define EFD 5    // edge types
#define MFD 64   // message features
#define THREADS 256   // 4 waves; wave = 4 rows x 16 m

typedef const __attribute__((address_space(1))) void* gas_ptr;
typedef __attribute__((address_space(3))) void*       las_ptr;

// Block = 16 rows x 16 m-quarter. Grid = 16 b * 4 rowtiles * 4 mq = 256.
// Splitting m across blocks cuts staged W 80->20 KB: chip staging burst
// 25 MB -> ~9 MB through the poison-dirtied cold cache (the R8 bottleneck).
__global__ __launch_bounds__(THREADS)
void ggnn_msgpass_kernel(const float* __restrict__ afm,    // (B,N,NF)
                         const int*   __restrict__ bfm,    // (B,N,N)
                         const int*   __restrict__ a_bfm,  // (B,N)
                         const float* __restrict__ adj_w,  // (EF,MF,NF)
                         const float* __restrict__ adj_a,  // (AEF,MF)
                         const float* __restrict__ bias,   // (MF)
                         float* __restrict__ out)          // (B,N,MF)
{
    __shared__ float afm_s[NN * NFD];              // 16 KB (all rows j)
    __shared__ float W_s[EFD * 16 * NFD];          // 20 KB: [e][mlocal][n]

    const int t    = threadIdx.x;
    const int lane = t & 63;
    const int g    = t >> 6;                 // wave id
    const int bx   = blockIdx.x;
    const int b    = bx >> 4;                // 16 blocks per batch
    const int i0   = ((bx & 15) >> 2) * 16;  // row-tile base (16 rows)
    const int mb   = (bx & 3) * 16;          // m-quarter base
    const int ir   = i0 + g * 4;             // this wave's first row

    // ---- bulk async global->LDS DMA, all issues outstanding at once ----
    // W slice: 20 issues of 1 KB; issue q: e=q>>2, mg=q&3 covers mlocal 4*mg..+3
    {
        const float4* wsrc = (const float4*)adj_w;
#pragma unroll
        for (int k = 0; k < 5; ++k) {
            int q  = g * 5 + k;                       // wave-uniform
            int e  = q >> 2, mg = q & 3;
            int sf4 = e * 1024 + mb * 16 + mg * 64;   // float4 index in adj_w
            __builtin_amdgcn_global_load_lds((gas_ptr)(wsrc + sf4 + lane),
                                             (las_ptr)(W_s + e * 1024 + mg * 256),
                                             16, 0, 0);
        }
        const float4* asrc = (const float4*)(afm + (size_t)b * NN * NFD);
#pragma unroll
        for (int k = 0; k < 4; ++k) {
            int q = g * 4 + k;
            __builtin_amdgcn_global_load_lds((gas_ptr)(asrc + q * 64 + lane),
                                             (las_ptr)(afm_s + q * 256),
                                             16, 0, 0);
        }
    }

    // ---- per-wave bfm rows (4) into registers, under the DMA shadow ----
    int bfm_reg[4];
#pragma unroll
    for (int r = 0; r < 4; ++r)
        bfm_reg[r] = bfm[((size_t)b * NN + ir + r) * NN + lane];

    // epilogue indices: lane L -> (row = L>>4, mlocal = L&15)
    const int   a_e  = a_bfm[b * NN + ir + (lane >> 4)];
    const float bv   = bias[mb + (lane & 15)];

    __syncthreads();   // drains DMA (vmcnt 0) + barrier

    const float att = (a_e > 0) ? adj_a[(size_t)(a_e - 1) * MFD + mb + (lane & 15)]
                                : 0.f;

    // ---- phase 2: bucket sums ac[r][e], lane = n. One afm read serves all
    // 4 rows; e wave-uniform (readlane const-idx) -> s_cselect + v_fmac ----
    float ac[4][EFD];
#pragma unroll
    for (int r = 0; r < 4; ++r)
#pragma unroll
        for (int e = 0; e < EFD; ++e) ac[r][e] = 0.f;

#pragma unroll
    for (int j = 0; j < NN; ++j) {
        float v = afm_s[j * NFD + lane];
#pragma unroll
        for (int r = 0; r < 4; ++r) {
            int e = __builtin_amdgcn_readlane(bfm_reg[r], j);
            ac[r][0] = fmaf((e == 1) ? 1.f : 0.f, v, ac[r][0]);
            ac[r][1] = fmaf((e == 2) ? 1.f : 0.f, v, ac[r][1]);
            ac[r][2] = fmaf((e == 3) ? 1.f : 0.f, v, ac[r][2]);
            ac[r][3] = fmaf((e == 4) ? 1.f : 0.f, v, ac[r][3]);
            ac[r][4] = fmaf((e == 5) ? 1.f : 0.f, v, ac[r][4]);
        }
    }

    // ---- phase 3: p[r*16+ml] = sum_e W_s[e][ml][lane] * ac[r][e].
    // 80 ds_read_b32 per lane (stride-4B across lanes -> conflict-free),
    // each W value reused across 4 rows ----
    float p[64];
#pragma unroll
    for (int ml = 0; ml < 16; ++ml) {
        float w0 = W_s[0 * 1024 + ml * NFD + lane];
        float w1 = W_s[1 * 1024 + ml * NFD + lane];
        float w2 = W_s[2 * 1024 + ml * NFD + lane];
        float w3 = W_s[3 * 1024 + ml * NFD + lane];
        float w4 = W_s[4 * 1024 + ml * NFD + lane];
#pragma unroll
        for (int r = 0; r < 4; ++r)
            p[r * 16 + ml] = w0 * ac[r][0] + w1 * ac[r][1] + w2 * ac[r][2]
                           + w3 * ac[r][3] + w4 * ac[r][4];
    }

    // ---- register butterfly transpose-reduce (verified R7/R8): folds the
    // 64 per-lane partials into the lane dim; lane L ends with idx L ----
#pragma unroll
    for (int s = 32; s >= 1; s >>= 1) {
#pragma unroll
        for (int m = 0; m < s; ++m) {
            float lo = p[m], hi = p[m + s];
            bool upper  = (lane & s) != 0;
            float mine  = upper ? hi : lo;
            float other = upper ? lo : hi;
            float recv  = __shfl_xor(other, s, 64);
            p[m] = mine + recv;
        }
    }
    float r = p[0];   // = msg[ir + (lane>>4)][mb + (lane&15)]

    // ---- epilogue: attention scale + bias; 4x 64B segmented store ----
    out[((size_t)b * NN + ir + (lane >> 4)) * MFD + mb + (lane & 15)] = r * att + bv;
}

extern "C" void kernel_launch(void* const* d_in, const int* in_sizes, int n_in,
                              void* d_out, int out_size, void* d_ws, size_t ws_size,
                              hipStream_t stream) {
    const float* afm   = (const float*)d_in[0];
    const int*   bfm   = (const int*)d_in[1];
    const int*   a_bfm = (const int*)d_in[2];
    const float* adj_w = (const float*)d_in[3];
    const float* adj_a = (const float*)d_in[4];
    const float* bias  = (const float*)d_in[5];
    float* out = (float*)d_out;

    dim3 grid(256);     // 16 b * 4 rowtiles * 4 m-quarters
    dim3 block(THREADS);
    ggnn_msgpass_kernel<<<grid, block, 0, stream>>>(afm, bfm, a_bfm, adj_w,
                                                    adj_a, bias, out);
}

// Round 10
// 67.788 us; speedup vs baseline: 1.1202x; 1.1202x over previous
//
#include <hip/hip_runtime.h>

#define NB  16   // batch
#define NN  64   // nodes
#define NFD 64   // node features
#define EFD 5    // edge types
#define MFD 64   // message features
#define THREADS 256   // 4 waves

typedef const __attribute__((address_space(1))) void* gas_ptr;
typedef __attribute__((address_space(3))) void*       las_ptr;

// Block = 4 rows x all 64 m. Phase 2: wave = 1 row (cheap, R8-style).
// Phase 3: wave = m-quarter, W in REGISTERS (loads overlap phase 2),
// ac exchanged via 5KB LDS. Kills R8's 320-ds_read/lane phase 3 and the
// full-DMA drain at the barrier.
__global__ __launch_bounds__(THREADS)
void ggnn_msgpass_kernel(const float* __restrict__ afm,    // (B,N,NF)
                         const int*   __restrict__ bfm,    // (B,N,N)
                         const int*   __restrict__ a_bfm,  // (B,N)
                         const float* __restrict__ adj_w,  // (EF,MF,NF)
                         const float* __restrict__ adj_a,  // (AEF,MF)
                         const float* __restrict__ bias,   // (MF)
                         float* __restrict__ out)          // (B,N,MF)
{
    __shared__ float afm_s[NN * NFD];        // 16 KB
    __shared__ float ac_s[4][EFD][NFD];      // 5 KB: per-row bucket sums

    const int t    = threadIdx.x;
    const int lane = t & 63;
    const int g    = t >> 6;            // wave id
    const int bx   = blockIdx.x;        // 256 blocks = 16 b * 16 rowtiles
    const int b    = bx >> 4;
    const int i0   = (bx & 15) << 2;    // 4 rows per block
    const int i    = i0 + g;            // phase-2 row of this wave

    // ---- async DMA: afm[b] only (16 KB, 4 issues/wave, fire-and-forget) ----
    {
        const float4* asrc = (const float4*)(afm + (size_t)b * NN * NFD);
#pragma unroll
        for (int k = 0; k < 4; ++k) {
            int q = g * 4 + k;
            __builtin_amdgcn_global_load_lds((gas_ptr)(asrc + q * 64 + lane),
                                             (las_ptr)(afm_s + q * 256),
                                             16, 0, 0);
        }
    }

    // ---- small loads under the DMA shadow ----
    const int   bfm_reg = bfm[((size_t)b * NN + i) * NN + lane]; // lane j = type(i,j)
    // epilogue mapping (phase 3): lane L -> row i0+(L>>4), m = g*16+(L&15)
    const int   a_row = a_bfm[b * NN + i0 + (lane >> 4)];
    const float bv    = bias[g * 16 + (lane & 15)];
    const float att   = (a_row > 0)
                      ? adj_a[(size_t)(a_row - 1) * MFD + g * 16 + (lane & 15)]
                      : 0.f;

    __syncthreads();   // barrier #1: afm_s ready (drains DMA + small loads)

    // ---- issue W-quarter loads into REGISTERS; latency hides under phase 2.
    // wv[e*16+ml] = W[e][g*16+ml][lane]; 80 coalesced 256B wave-loads ----
    float wv[80];
#pragma unroll
    for (int p = 0; p < 80; ++p)
        wv[p] = adj_w[(size_t)(p / 16) * MFD * NFD + (g * 16 + (p % 16)) * NFD + lane];

    // ---- phase 2 (R8-style, 1 row/wave): bucket sums, lane = n ----
    float ac0 = 0.f, ac1 = 0.f, ac2 = 0.f, ac3 = 0.f, ac4 = 0.f;
#pragma unroll
    for (int j = 0; j < NN; ++j) {
        float v = afm_s[j * NFD + lane];
        int e = __builtin_amdgcn_readlane(bfm_reg, j);
        ac0 = fmaf((e == 1) ? 1.f : 0.f, v, ac0);
        ac1 = fmaf((e == 2) ? 1.f : 0.f, v, ac1);
        ac2 = fmaf((e == 3) ? 1.f : 0.f, v, ac2);
        ac3 = fmaf((e == 4) ? 1.f : 0.f, v, ac3);
        ac4 = fmaf((e == 5) ? 1.f : 0.f, v, ac4);
    }
    ac_s[g][0][lane] = ac0;
    ac_s[g][1][lane] = ac1;
    ac_s[g][2][lane] = ac2;
    ac_s[g][3][lane] = ac3;
    ac_s[g][4][lane] = ac4;

    __syncthreads();   // barrier #2: ac_s ready (drains W regs too — tail only)

    // ---- phase 3: wave g = m-quarter for ALL 4 rows. Only 20 LDS reads ----
    float acr[4][EFD];
#pragma unroll
    for (int r = 0; r < 4; ++r)
#pragma unroll
        for (int e = 0; e < EFD; ++e)
            acr[r][e] = ac_s[r][e][lane];

    float p[64];   // p[r*16+ml] = partial of (row i0+r, m=g*16+ml) at n=lane
#pragma unroll
    for (int r = 0; r < 4; ++r)
#pragma unroll
        for (int ml = 0; ml < 16; ++ml)
            p[r * 16 + ml] = wv[0 * 16 + ml] * acr[r][0]
                           + wv[1 * 16 + ml] * acr[r][1]
                           + wv[2 * 16 + ml] * acr[r][2]
                           + wv[3 * 16 + ml] * acr[r][3]
                           + wv[4 * 16 + ml] * acr[r][4];

    // ---- verified butterfly transpose-reduce: final lane L = sum_lanes p[L] ----
#pragma unroll
    for (int s = 32; s >= 1; s >>= 1) {
#pragma unroll
        for (int m = 0; m < s; ++m) {
            float lo = p[m], hi = p[m + s];
            bool upper  = (lane & s) != 0;
            float mine  = upper ? hi : lo;
            float other = upper ? lo : hi;
            float recv  = __shfl_xor(other, s, 64);
            p[m] = mine + recv;
        }
    }
    float res = p[0];  // = msg[i0+(lane>>4)][g*16+(lane&15)]

    // ---- epilogue: attention scale + bias; 4x 64B segments per wave ----
    out[((size_t)b * NN + i0 + (lane >> 4)) * MFD + g * 16 + (lane & 15)]
        = res * att + bv;
}

extern "C" void kernel_launch(void* const* d_in, const int* in_sizes, int n_in,
                              void* d_out, int out_size, void* d_ws, size_t ws_size,
                              hipStream_t stream) {
    const float* afm   = (const float*)d_in[0];
    const int*   bfm   = (const int*)d_in[1];
    const int*   a_bfm = (const int*)d_in[2];
    const float* adj_w = (const float*)d_in[3];
    const float* adj_a = (const float*)d_in[4];
    const float* bias  = (const float*)d_in[5];
    float* out = (float*)d_out;

    dim3 grid(256);     // 16 b * 16 rowtiles (4 rows each)
    dim3 block(THREADS);
    ggnn_msgpass_kernel<<<grid, block, 0, stream>>>(afm, bfm, a_bfm, adj_w,
                                                    adj_a, bias, out);
}